// Round 11
// baseline (1481.387 us; speedup 1.0000x reference)
//
#include <hip/hip_runtime.h>
#include <hip/hip_bf16.h>

// ---------------------------------------------------------------------------
// InterpretableMultiHeadAttention  (B=8, S=1024, D=1024, H=16, dk=64)
//   outputs [B,S,D] fp32 ; attn [B,Sq,H,Sk] fp32  (concatenated in d_out)
//
// ABLATION ROUND: attn has been ~290-300us across 4 different schedules
// (R5/R7/R8/R10) with no counter at a ceiling.  Theory keeps failing ->
// measure phase costs directly.  vqk/vpv/vst each run ONE phase of the attn
// kernel 4x (to clear the ~340us top-5 profile cutoff).  vst writes garbage
// to the real attn output region; the real attn kernel runs afterwards and
// overwrites it (stream-ordered => deterministic, correct final output).
// Production path = R8 kernels verbatim (best passing config, 425us).
// ---------------------------------------------------------------------------

typedef __attribute__((ext_vector_type(4))) float f32x4;
typedef __attribute__((ext_vector_type(8))) short bf16x8;
typedef __attribute__((ext_vector_type(4))) short short4v;
typedef __attribute__((ext_vector_type(2))) unsigned int uint2v;

#define MFMA16(a, b, c) __builtin_amdgcn_mfma_f32_16x16x32_bf16((a), (b), (c), 0, 0, 0)

__device__ __forceinline__ unsigned int rne16(float f) {
  unsigned int u = __float_as_uint(f);
  return u + 0x7fffu + ((u >> 16) & 1u);   // round-to-nearest-even in bit 16
}
__device__ __forceinline__ unsigned int pack2bf(float a, float b) {
  return (rne16(a) >> 16) | (rne16(b) & 0xffff0000u);
}
__device__ __forceinline__ short f2bf(float f) {
  return (short)(rne16(f) >> 16);
}
__device__ __forceinline__ float bf2f(short s) {
  return __uint_as_float(((unsigned int)(unsigned short)s) << 16);
}

// ---------------------------------------------------------------------------
// Kernel 1: fused Q/K projection (unchanged).
// ---------------------------------------------------------------------------
__global__ __launch_bounds__(256) void proj_qk_kernel(
    const float* __restrict__ qin, const float* __restrict__ kin,
    const float* __restrict__ Wq, const float* __restrict__ Wk,
    __hip_bfloat16* __restrict__ qs, __hip_bfloat16* __restrict__ ks)
{
  const int K = 1024, N = 1024;
  __shared__ short a_lds[128][40];
  __shared__ short b_lds[128][40];
  const int tid  = threadIdx.x;
  const int lane = tid & 63, wid = tid >> 6;
  const int g = lane >> 4, r = lane & 15;
  const bool isK = blockIdx.y >= 8;
  const float* A = isK ? kin : qin;
  const float* W = isK ? Wk : Wq;
  __hip_bfloat16* C = isK ? ks : qs;
  const float scale = isK ? 1.0f : 0.125f;
  const int m0 = blockIdx.x * 128;
  const int n0 = (blockIdx.y & 7) * 128;
  const int wm = (wid >> 1) * 64, wn = (wid & 1) * 64;
  const int lrow = tid >> 3, lcol = (tid & 7) * 4;

  f32x4 acc[4][4];
#pragma unroll
  for (int i = 0; i < 4; ++i)
#pragma unroll
    for (int j = 0; j < 4; ++j) acc[i][j] = (f32x4){0.f, 0.f, 0.f, 0.f};

  for (int k0 = 0; k0 < K; k0 += 32) {
    float4 av[4], wv[4];
#pragma unroll
    for (int p = 0; p < 4; ++p) {
      av[p] = *(const float4*)&A[(m0 + lrow + p * 32) * K + k0 + lcol];
      wv[p] = *(const float4*)&W[(n0 + lrow + p * 32) * K + k0 + lcol];
    }
    __syncthreads();
#pragma unroll
    for (int p = 0; p < 4; ++p) {
      uint2v ua = {pack2bf(av[p].x, av[p].y), pack2bf(av[p].z, av[p].w)};
      uint2v uw = {pack2bf(wv[p].x, wv[p].y), pack2bf(wv[p].z, wv[p].w)};
      *(uint2v*)&a_lds[lrow + p * 32][lcol] = ua;
      *(uint2v*)&b_lds[lrow + p * 32][lcol] = uw;
    }
    __syncthreads();
    bf16x8 af[4], bf[4];
#pragma unroll
    for (int t = 0; t < 4; ++t) {
      af[t] = *(bf16x8*)&a_lds[wm + t * 16 + r][g * 8];
      bf[t] = *(bf16x8*)&b_lds[wn + t * 16 + r][g * 8];
    }
#pragma unroll
    for (int mt = 0; mt < 4; ++mt)
#pragma unroll
      for (int nt = 0; nt < 4; ++nt)
        acc[mt][nt] = MFMA16(af[mt], bf[nt], acc[mt][nt]);
  }

#pragma unroll
  for (int mt = 0; mt < 4; ++mt)
#pragma unroll
    for (int nt = 0; nt < 4; ++nt) {
      const int n = n0 + wn + nt * 16 + r;
#pragma unroll
      for (int j = 0; j < 4; ++j) {
        const int m = m0 + wm + mt * 16 + 4 * g + j;
        C[m * N + n] = __float2bfloat16(acc[mt][nt][j] * scale);
      }
    }
}

// ---------------------------------------------------------------------------
// Kernel 2: V projection (unchanged).
// ---------------------------------------------------------------------------
__global__ __launch_bounds__(256) void proj_v_kernel(
    const float* __restrict__ vin, const float* __restrict__ Wv,
    __hip_bfloat16* __restrict__ vsT)
{
  const int K = 1024;
  __shared__ short a_lds[128][40];
  __shared__ short b_lds[64][40];
  const int tid  = threadIdx.x;
  const int lane = tid & 63, wid = tid >> 6;
  const int g = lane >> 4, r = lane & 15;
  const int m0 = blockIdx.x * 128;
  const int wm = wid * 32;
  const int lrow = tid >> 3, lcol = (tid & 7) * 4;

  f32x4 acc[2][4];
#pragma unroll
  for (int i = 0; i < 2; ++i)
#pragma unroll
    for (int j = 0; j < 4; ++j) acc[i][j] = (f32x4){0.f, 0.f, 0.f, 0.f};

  for (int k0 = 0; k0 < K; k0 += 32) {
    float4 av[4], wv2[2];
#pragma unroll
    for (int p = 0; p < 4; ++p)
      av[p] = *(const float4*)&vin[(m0 + lrow + p * 32) * K + k0 + lcol];
#pragma unroll
    for (int p = 0; p < 2; ++p)
      wv2[p] = *(const float4*)&Wv[(lrow + p * 32) * K + k0 + lcol];
    __syncthreads();
#pragma unroll
    for (int p = 0; p < 4; ++p) {
      uint2v ua = {pack2bf(av[p].x, av[p].y), pack2bf(av[p].z, av[p].w)};
      *(uint2v*)&a_lds[lrow + p * 32][lcol] = ua;
    }
#pragma unroll
    for (int p = 0; p < 2; ++p) {
      uint2v uw = {pack2bf(wv2[p].x, wv2[p].y), pack2bf(wv2[p].z, wv2[p].w)};
      *(uint2v*)&b_lds[lrow + p * 32][lcol] = uw;
    }
    __syncthreads();
    bf16x8 af[2], bf[4];
#pragma unroll
    for (int t = 0; t < 2; ++t) af[t] = *(bf16x8*)&a_lds[wm + t * 16 + r][g * 8];
#pragma unroll
    for (int t = 0; t < 4; ++t) bf[t] = *(bf16x8*)&b_lds[t * 16 + r][g * 8];
#pragma unroll
    for (int mt = 0; mt < 2; ++mt)
#pragma unroll
      for (int nt = 0; nt < 4; ++nt)
        acc[mt][nt] = MFMA16(af[mt], bf[nt], acc[mt][nt]);
  }

#pragma unroll
  for (int mt = 0; mt < 2; ++mt)
#pragma unroll
    for (int nt = 0; nt < 4; ++nt) {
      const int e = nt * 16 + r;
#pragma unroll
      for (int j = 0; j < 4; ++j) {
        const int m = m0 + wm + mt * 16 + 4 * g + j;
        const int b = m >> 10, t = m & 1023;
        vsT[b * 65536 + e * 1024 + t] = __float2bfloat16(acc[mt][nt][j]);
      }
    }
}

// ---------------------------------------------------------------------------
// ABLATION Kernel A: QK phase only, x REPS.  Same grid/geometry as attn.
// K loads + MFMA + exp + pack + l-reduce.  Values kept live via asm sinks.
// ---------------------------------------------------------------------------
template <int REPS>
__global__ __launch_bounds__(256, 4) void vqk_kernel(
    const __hip_bfloat16* __restrict__ qs_, const __hip_bfloat16* __restrict__ ks_)
{
  const int S = 1024;
  const int tid = threadIdx.x, lane = tid & 63, kc = tid >> 6;
  const int g = lane >> 4, r = lane & 15;
  const int h = blockIdx.y, b = blockIdx.z;
  const int qrow = blockIdx.x * 16;
  __shared__ float l_lds[4][16];

  const short* qsp = (const short*)qs_;
  const short* ksp = (const short*)ks_;
  const int qidx = (b * S + qrow + r) * 1024 + h * 64;
  const bf16x8 qf0 = *(const bf16x8*)&qsp[qidx + g * 8];
  const bf16x8 qf1 = *(const bf16x8*)&qsp[qidx + 32 + g * 8];
  const int kbase = (b * S + kc * 256 + r) * 1024 + h * 64 + g * 8;

  unsigned int chk = 0;
  float lsink = 0.f;
  for (int rep = 0; rep < REPS; ++rep) {
    unsigned int pk[32];
    float lsa0 = 0.f, lsa1 = 0.f, lsa2 = 0.f, lsa3 = 0.f;
#pragma unroll
    for (int i = 0; i < 4; ++i) {
      const int t0 = i * 64;
      bf16x8 kf[8];
#pragma unroll
      for (int u = 0; u < 4; ++u) {
        kf[2 * u]     = *(const bf16x8*)&ksp[kbase + (t0 + 16 * u) * 1024];
        kf[2 * u + 1] = *(const bf16x8*)&ksp[kbase + (t0 + 16 * u) * 1024 + 32];
      }
      float es[4];
#pragma unroll
      for (int u = 0; u < 4; ++u) {
        f32x4 s = (f32x4){0.f, 0.f, 0.f, 0.f};
        s = MFMA16(kf[2 * u], qf0, s);
        s = MFMA16(kf[2 * u + 1], qf1, s);
        const float e0 = __expf(s[0]), e1 = __expf(s[1]);
        const float e2 = __expf(s[2]), e3 = __expf(s[3]);
        pk[i * 8 + 2 * u]     = pack2bf(e0, e1);
        pk[i * 8 + 2 * u + 1] = pack2bf(e2, e3);
        es[u] = (e0 + e1) + (e2 + e3);
      }
      lsa0 += es[0]; lsa1 += es[1]; lsa2 += es[2]; lsa3 += es[3];
    }
    float ls = (lsa0 + lsa1) + (lsa2 + lsa3);
    ls += __shfl_xor(ls, 16);
    ls += __shfl_xor(ls, 32);
    if (g == 0) l_lds[kc][r] = ls;
    __syncthreads();
    lsink += (l_lds[0][r] + l_lds[1][r]) + (l_lds[2][r] + l_lds[3][r]);
#pragma unroll
    for (int j = 0; j < 32; ++j) chk ^= pk[j];
    __syncthreads();
  }
  asm volatile("" ::"v"(chk), "v"(lsink));   // keep everything live (no DCE)
}

// ---------------------------------------------------------------------------
// ABLATION Kernel B: PV phase only (LDS stage + V loads + MFMA), x REPS.
// Synthetic P (no K reads).  hacc kept live via asm sinks.
// ---------------------------------------------------------------------------
template <int REPS>
__global__ __launch_bounds__(256, 4) void vpv_kernel(
    const __hip_bfloat16* __restrict__ vsT_)
{
  const int tid = threadIdx.x, lane = tid & 63, kc = tid >> 6;
  const int g = lane >> 4, r = lane & 15;
  const int b = blockIdx.z;
  __shared__ short p_big[4][16][260];

  const short* vsp = (const short*)vsT_;
  // synthetic small bf16 pattern (exp 120 -> ~0.0078), lane-dependent
  const unsigned int seed = 0x3C003C00u | (lane & 3u) | ((lane & 12u) << 14);
#pragma unroll
  for (int j = 0; j < 8; ++j) {
    uint2v w = {seed + j, seed ^ (j * 0x00010001u)};
    *(uint2v*)&p_big[kc][r][j * 32 + 4 * g] = w;
    *(uint2v*)&p_big[kc][r][j * 32 + 16 + 4 * g] = w;
  }
  asm volatile("s_waitcnt lgkmcnt(0)" ::: "memory");

  f32x4 hacc[4];
#pragma unroll
  for (int i = 0; i < 4; ++i) hacc[i] = (f32x4){0.f, 0.f, 0.f, 0.f};
  const int vbase = b * 65536 + r * 1024 + g * 8 + kc * 256;

  for (int rep = 0; rep < REPS; ++rep) {
#pragma unroll
    for (int j = 0; j < 8; ++j) {
      const int tcl = j * 32;
      bf16x8 vf[4];
#pragma unroll
      for (int nt = 0; nt < 4; ++nt)
        vf[nt] = *(const bf16x8*)&vsp[vbase + nt * 16384 + tcl];
      const bf16x8 pa = *(bf16x8*)&p_big[kc][r][tcl + g * 8];
#pragma unroll
      for (int nt = 0; nt < 4; ++nt)
        hacc[nt] = MFMA16(pa, vf[nt], hacc[nt]);
    }
  }
#pragma unroll
  for (int nt = 0; nt < 4; ++nt)
#pragma unroll
    for (int j = 0; j < 4; ++j)
      asm volatile("" ::"v"(hacc[nt][j]));
}

// ---------------------------------------------------------------------------
// ABLATION Kernel C: attn NT-store phase only, x REPS.  Writes garbage to the
// REAL attn region (real attn kernel overwrites it afterwards).
// ---------------------------------------------------------------------------
template <int REPS>
__global__ __launch_bounds__(256, 4) void vst_kernel(float* __restrict__ attn_out)
{
  const int S = 1024, H = 16;
  const int tid = threadIdx.x, lane = tid & 63, kc = tid >> 6;
  const int g = lane >> 4, r = lane & 15;
  const int h = blockIdx.y, b = blockIdx.z;
  const int qrow = blockIdx.x * 16;
  __shared__ short p_big[4][16][260];

  const unsigned int seed = 0x3C003C00u | (lane & 3u);
#pragma unroll
  for (int j = 0; j < 8; ++j) {
    uint2v w = {seed + j, seed ^ j};
    *(uint2v*)&p_big[kc][r][j * 32 + 4 * g] = w;
    *(uint2v*)&p_big[kc][r][j * 32 + 16 + 4 * g] = w;
  }
  __syncthreads();

  for (int rep = 0; rep < REPS; ++rep) {
    const int half = lane >> 5, l32 = lane & 31;
    const float invr = 1.0f + rep * 1e-7f;   // rep-dependent: no CSE across reps
#pragma unroll
    for (int rp = 0; rp < 8; ++rp) {
      const int row = rp * 2 + half;
      const bf16x8 pe = *(const bf16x8*)&p_big[kc][row][l32 * 8];
      f32x4 o0, o1;
      o0[0] = bf2f(pe[0]) * invr; o0[1] = bf2f(pe[1]) * invr;
      o0[2] = bf2f(pe[2]) * invr; o0[3] = bf2f(pe[3]) * invr;
      o1[0] = bf2f(pe[4]) * invr; o1[1] = bf2f(pe[5]) * invr;
      o1[2] = bf2f(pe[6]) * invr; o1[3] = bf2f(pe[7]) * invr;
      const int base = ((b * S + qrow + row) * H + h) * S + kc * 256 + l32 * 8;
      __builtin_nontemporal_store(o0, (f32x4*)&attn_out[base]);
      __builtin_nontemporal_store(o1, (f32x4*)&attn_out[base + 4]);
    }
  }
}

// ---------------------------------------------------------------------------
// Kernel 3: fused attention -- R8 version VERBATIM (best passing: 425us).
// ---------------------------------------------------------------------------
__global__ __launch_bounds__(256, 4) void attn_kernel(
    const __hip_bfloat16* __restrict__ qs_, const __hip_bfloat16* __restrict__ ks_,
    const __hip_bfloat16* __restrict__ vsT_, float* __restrict__ attn_out,
    __hip_bfloat16* __restrict__ heads_)
{
  const int S = 1024, H = 16;
  const int tid = threadIdx.x, lane = tid & 63, kc = tid >> 6;
  const int g = lane >> 4, r = lane & 15;
  const int h = blockIdx.y, b = blockIdx.z;
  const int bh = b * H + h;
  const int qrow = blockIdx.x * 16;

  __shared__ short p_big[4][16][260];
  __shared__ float l_lds[4][16];
  __shared__ float inv_lds[16];
  float (*heads_ov)[16][80] = (float (*)[16][80])p_big;

  const short* qsp = (const short*)qs_;
  const short* ksp = (const short*)ks_;
  const short* vsp = (const short*)vsT_;
  short* headsp = (short*)heads_;

  const int qidx = (b * S + qrow + r) * 1024 + h * 64;
  const bf16x8 qf0 = *(const bf16x8*)&qsp[qidx + g * 8];
  const bf16x8 qf1 = *(const bf16x8*)&qsp[qidx + 32 + g * 8];
  const int kbase = (b * S + kc * 256 + r) * 1024 + h * 64 + g * 8;

  unsigned int pk[32];
  float lsa0 = 0.f, lsa1 = 0.f, lsa2 = 0.f, lsa3 = 0.f;
#pragma unroll
  for (int i = 0; i < 4; ++i) {
    const int t0 = i * 64;
    bf16x8 kf[8];
#pragma unroll
    for (int u = 0; u < 4; ++u) {
      kf[2 * u]     = *(const bf16x8*)&ksp[kbase + (t0 + 16 * u) * 1024];
      kf[2 * u + 1] = *(const bf16x8*)&ksp[kbase + (t0 + 16 * u) * 1024 + 32];
    }
    float es[4];
#pragma unroll
    for (int u = 0; u < 4; ++u) {
      f32x4 s = (f32x4){0.f, 0.f, 0.f, 0.f};
      s = MFMA16(kf[2 * u], qf0, s);
      s = MFMA16(kf[2 * u + 1], qf1, s);
      const float e0 = __expf(s[0]), e1 = __expf(s[1]);
      const float e2 = __expf(s[2]), e3 = __expf(s[3]);
      pk[i * 8 + 2 * u]     = pack2bf(e0, e1);
      pk[i * 8 + 2 * u + 1] = pack2bf(e2, e3);
      es[u] = (e0 + e1) + (e2 + e3);
    }
    lsa0 += es[0]; lsa1 += es[1]; lsa2 += es[2]; lsa3 += es[3];
  }
  float ls = (lsa0 + lsa1) + (lsa2 + lsa3);
  ls += __shfl_xor(ls, 16);
  ls += __shfl_xor(ls, 32);
  if (g == 0) l_lds[kc][r] = ls;
  __syncthreads();
  {
    const float lf = (l_lds[0][r] + l_lds[1][r]) + (l_lds[2][r] + l_lds[3][r]);
    if (kc == 0 && g == 0) inv_lds[r] = 1.f / lf;
  }

#pragma unroll
  for (int j = 0; j < 8; ++j) {
    uint2v w0 = {pk[4 * j + 0], pk[4 * j + 1]};
    uint2v w1 = {pk[4 * j + 2], pk[4 * j + 3]};
    *(uint2v*)&p_big[kc][r][j * 32 + 4 * g] = w0;
    *(uint2v*)&p_big[kc][r][j * 32 + 16 + 4 * g] = w1;
  }
  __syncthreads();

  f32x4 hacc[4];
#pragma unroll
  for (int i = 0; i < 4; ++i) hacc[i] = (f32x4){0.f, 0.f, 0.f, 0.f};
  const int vbase = b * 65536 + r * 1024 + g * 8 + kc * 256;

#pragma unroll
  for (int j = 0; j < 8; ++j) {
    const int tcl = j * 32;
    bf16x8 vf[4];
#pragma unroll
    for (int nt = 0; nt < 4; ++nt)
      vf[nt] = *(const bf16x8*)&vsp[vbase + nt * 16384 + tcl];
    const bf16x8 pa = *(bf16x8*)&p_big[kc][r][tcl + g * 8];
#pragma unroll
    for (int nt = 0; nt < 4; ++nt)
      hacc[nt] = MFMA16(pa, vf[nt], hacc[nt]);
  }

  {
    const int half = lane >> 5, l32 = lane & 31;
#pragma unroll
    for (int rp = 0; rp < 8; ++rp) {
      const int row = rp * 2 + half;
      const bf16x8 pe = *(const bf16x8*)&p_big[kc][row][l32 * 8];
      const float invr = inv_lds[row];
      f32x4 o0, o1;
      o0[0] = bf2f(pe[0]) * invr; o0[1] = bf2f(pe[1]) * invr;
      o0[2] = bf2f(pe[2]) * invr; o0[3] = bf2f(pe[3]) * invr;
      o1[0] = bf2f(pe[4]) * invr; o1[1] = bf2f(pe[5]) * invr;
      o1[2] = bf2f(pe[6]) * invr; o1[3] = bf2f(pe[7]) * invr;
      const int base = ((b * S + qrow + row) * H + h) * S + kc * 256 + l32 * 8;
      __builtin_nontemporal_store(o0, (f32x4*)&attn_out[base]);
      __builtin_nontemporal_store(o1, (f32x4*)&attn_out[base + 4]);
    }
  }
  __syncthreads();

#pragma unroll
  for (int nt = 0; nt < 4; ++nt)
#pragma unroll
    for (int j = 0; j < 4; ++j)
      heads_ov[kc][4 * g + j][nt * 16 + r] = hacc[nt][j];
  __syncthreads();

  {
    const int row = tid >> 4, c4 = (tid & 15) * 4;
    const float invr = inv_lds[row];
    short4v hv;
#pragma unroll
    for (int i = 0; i < 4; ++i) {
      const float s4 = (heads_ov[0][row][c4 + i] + heads_ov[1][row][c4 + i]) +
                       (heads_ov[2][row][c4 + i] + heads_ov[3][row][c4 + i]);
      hv[i] = f2bf(s4 * invr);
    }
    *(short4v*)&headsp[((bh * S + qrow + row)) * 64 + c4] = hv;
  }
}

// ---------------------------------------------------------------------------
// Kernel 4: outputs = mean_h(heads) @ Wo^T (R8 version, bf16 heads).
// ---------------------------------------------------------------------------
__global__ __launch_bounds__(256) void out_kernel(
    const __hip_bfloat16* __restrict__ heads_, const float* __restrict__ Wo,
    float* __restrict__ out)
{
  __shared__ float hm[16][64];
  const int tid = threadIdx.x;
  const int m0 = blockIdx.x * 16;
  const short* headsp = (const short*)heads_;

  {
    const int row = tid >> 4, e4 = (tid & 15) * 4;
    const int m = m0 + row, b = m >> 10, s = m & 1023;
    float a0 = 0.f, a1 = 0.f, a2 = 0.f, a3 = 0.f;
    for (int hh = 0; hh < 16; ++hh) {
      const short4v hv =
          *(const short4v*)&headsp[((b * 16 + hh) * 1024 + s) * 64 + e4];
      a0 += bf2f(hv[0]); a1 += bf2f(hv[1]); a2 += bf2f(hv[2]); a3 += bf2f(hv[3]);
    }
    const float sc = 1.f / 16.f;
    hm[row][e4 + 0] = a0 * sc; hm[row][e4 + 1] = a1 * sc;
    hm[row][e4 + 2] = a2 * sc; hm[row][e4 + 3] = a3 * sc;
  }
  __syncthreads();

  for (int c = 0; c < 4; ++c) {
    const int d = c * 256 + tid;
    float4 wo4[16];
#pragma unroll
    for (int i = 0; i < 16; ++i) wo4[i] = *(const float4*)&Wo[d * 64 + i * 4];
    for (int row = 0; row < 16; ++row) {
      float a = 0.f;
#pragma unroll
      for (int i = 0; i < 16; ++i) {
        const float4 h4 = *(const float4*)&hm[row][i * 4];
        a += h4.x * wo4[i].x + h4.y * wo4[i].y + h4.z * wo4[i].z + h4.w * wo4[i].w;
      }
      out[(m0 + row) * 1024 + d] = a;
    }
  }
}

// ---------------------------------------------------------------------------
extern "C" void kernel_launch(void* const* d_in, const int* in_sizes, int n_in,
                              void* d_out, int out_size, void* d_ws, size_t ws_size,
                              hipStream_t stream) {
  const float* q  = (const float*)d_in[0];
  const float* k  = (const float*)d_in[1];
  const float* v  = (const float*)d_in[2];
  const float* Wq = (const float*)d_in[3];
  const float* Wk = (const float*)d_in[4];
  const float* Wv = (const float*)d_in[5];
  const float* Wo = (const float*)d_in[6];

  float* out0 = (float*)d_out;                       // [8,1024,1024]
  float* attn = out0 + (size_t)8 * 1024 * 1024;      // [8,1024,16,1024]

  char* ws = (char*)d_ws;                            // 49 MB used
  __hip_bfloat16* qs    = (__hip_bfloat16*)(ws);                     // 16 MB
  __hip_bfloat16* ksbuf = (__hip_bfloat16*)(ws + (16u << 20));       // 16 MB
  __hip_bfloat16* vsT   = (__hip_bfloat16*)(ws + (32u << 20));       //  1 MB
  __hip_bfloat16* heads = (__hip_bfloat16*)(ws + (33u << 20));       // 16 MB

  dim3 agrid(64, 16, 8), blk(256);
  proj_qk_kernel<<<dim3(64, 16), blk, 0, stream>>>(q, k, Wq, Wk, qs, ksbuf);
  proj_v_kernel<<<dim3(64), blk, 0, stream>>>(v, Wv, vsT);

  // --- ablation probes (garbage results; vst's attn writes are overwritten
  //     by the real attn_kernel below; stream order makes this deterministic)
  vqk_kernel<4><<<agrid, blk, 0, stream>>>(qs, ksbuf);
  vpv_kernel<4><<<agrid, blk, 0, stream>>>(vsT);
  vst_kernel<4><<<agrid, blk, 0, stream>>>(attn);

  // --- production path (R8 verbatim)
  attn_kernel<<<agrid, blk, 0, stream>>>(qs, ksbuf, vsT, attn, heads);
  out_kernel<<<dim3(512), blk, 0, stream>>>(heads, Wo, out0);
}

// Round 12
// 426.310 us; speedup vs baseline: 3.4749x; 3.4749x over previous
//
#include <hip/hip_runtime.h>
#include <hip/hip_bf16.h>

// ---------------------------------------------------------------------------
// InterpretableMultiHeadAttention  (B=8, S=1024, D=1024, H=16, dk=64)
//   outputs [B,S,D] fp32 ; attn [B,Sq,H,Sk] fp32  (concatenated in d_out)
// Pipeline:
//   1) proj_qk : qs = (q @ Wq^T)/8, ks = k @ Wk^T   (bf16, [b,s,(h,e)] layout)
//   2) proj_v  : vsT = (v @ Wv^T)^T                 (bf16, [b][e][t] layout)
//   3) attn    : R8 structure + XCD-AWARE 1D GRID SWIZZLE.  R11 ablation:
//                QK phase = 154us/rep with 441 MB FETCH vs 16 MB unique K
//                (27x over-fetch) -- consecutive blocks round-robin across
//                8 XCD L2s, so every L2 fetches every (b,h) K-slice.
//                Swizzle lin=(bid&7)*1024+(bid>>3): XCD j owns batch j's
//                blocks -> K(2MB)+V(128KB) resident per 4MB L2.
//   4) out     : outputs = mean_h(heads) @ Wo^T     (VALU)
// All f32->bf16 conversions are round-to-nearest-even.
// ---------------------------------------------------------------------------

typedef __attribute__((ext_vector_type(4))) float f32x4;
typedef __attribute__((ext_vector_type(8))) short bf16x8;
typedef __attribute__((ext_vector_type(4))) short short4v;
typedef __attribute__((ext_vector_type(2))) unsigned int uint2v;

#define MFMA16(a, b, c) __builtin_amdgcn_mfma_f32_16x16x32_bf16((a), (b), (c), 0, 0, 0)

__device__ __forceinline__ unsigned int rne16(float f) {
  unsigned int u = __float_as_uint(f);
  return u + 0x7fffu + ((u >> 16) & 1u);   // round-to-nearest-even in bit 16
}
__device__ __forceinline__ unsigned int pack2bf(float a, float b) {
  return (rne16(a) >> 16) | (rne16(b) & 0xffff0000u);
}
__device__ __forceinline__ short f2bf(float f) {
  return (short)(rne16(f) >> 16);
}
__device__ __forceinline__ float bf2f(short s) {
  return __uint_as_float(((unsigned int)(unsigned short)s) << 16);
}

// ---------------------------------------------------------------------------
// Kernel 1: fused Q/K projection.  grid = (64, 16): y<8 -> Q, else K.
// ---------------------------------------------------------------------------
__global__ __launch_bounds__(256) void proj_qk_kernel(
    const float* __restrict__ qin, const float* __restrict__ kin,
    const float* __restrict__ Wq, const float* __restrict__ Wk,
    __hip_bfloat16* __restrict__ qs, __hip_bfloat16* __restrict__ ks)
{
  const int K = 1024, N = 1024;
  __shared__ short a_lds[128][40];   // padded stride 40 (80B) -> ~2-way banks
  __shared__ short b_lds[128][40];
  const int tid  = threadIdx.x;
  const int lane = tid & 63, wid = tid >> 6;
  const int g = lane >> 4, r = lane & 15;
  const bool isK = blockIdx.y >= 8;
  const float* A = isK ? kin : qin;
  const float* W = isK ? Wk : Wq;
  __hip_bfloat16* C = isK ? ks : qs;
  const float scale = isK ? 1.0f : 0.125f;   // 1/sqrt(dk)=1/8 folded into qs
  const int m0 = blockIdx.x * 128;
  const int n0 = (blockIdx.y & 7) * 128;
  const int wm = (wid >> 1) * 64, wn = (wid & 1) * 64;
  const int lrow = tid >> 3, lcol = (tid & 7) * 4;

  f32x4 acc[4][4];
#pragma unroll
  for (int i = 0; i < 4; ++i)
#pragma unroll
    for (int j = 0; j < 4; ++j) acc[i][j] = (f32x4){0.f, 0.f, 0.f, 0.f};

  for (int k0 = 0; k0 < K; k0 += 32) {
    float4 av[4], wv[4];
#pragma unroll
    for (int p = 0; p < 4; ++p) {
      av[p] = *(const float4*)&A[(m0 + lrow + p * 32) * K + k0 + lcol];
      wv[p] = *(const float4*)&W[(n0 + lrow + p * 32) * K + k0 + lcol];
    }
    __syncthreads();
#pragma unroll
    for (int p = 0; p < 4; ++p) {
      uint2v ua = {pack2bf(av[p].x, av[p].y), pack2bf(av[p].z, av[p].w)};
      uint2v uw = {pack2bf(wv[p].x, wv[p].y), pack2bf(wv[p].z, wv[p].w)};
      *(uint2v*)&a_lds[lrow + p * 32][lcol] = ua;
      *(uint2v*)&b_lds[lrow + p * 32][lcol] = uw;
    }
    __syncthreads();
    bf16x8 af[4], bf[4];
#pragma unroll
    for (int t = 0; t < 4; ++t) {
      af[t] = *(bf16x8*)&a_lds[wm + t * 16 + r][g * 8];
      bf[t] = *(bf16x8*)&b_lds[wn + t * 16 + r][g * 8];
    }
#pragma unroll
    for (int mt = 0; mt < 4; ++mt)
#pragma unroll
      for (int nt = 0; nt < 4; ++nt)
        acc[mt][nt] = MFMA16(af[mt], bf[nt], acc[mt][nt]);
  }

#pragma unroll
  for (int mt = 0; mt < 4; ++mt)
#pragma unroll
    for (int nt = 0; nt < 4; ++nt) {
      const int n = n0 + wn + nt * 16 + r;
#pragma unroll
      for (int j = 0; j < 4; ++j) {
        const int m = m0 + wm + mt * 16 + 4 * g + j;
        C[m * N + n] = __float2bfloat16(acc[mt][nt][j] * scale);
      }
    }
}

// ---------------------------------------------------------------------------
// Kernel 2: V projection, output TRANSPOSED per batch: vsT[b][e][t] bf16.
// ---------------------------------------------------------------------------
__global__ __launch_bounds__(256) void proj_v_kernel(
    const float* __restrict__ vin, const float* __restrict__ Wv,
    __hip_bfloat16* __restrict__ vsT)
{
  const int K = 1024;
  __shared__ short a_lds[128][40];
  __shared__ short b_lds[64][40];
  const int tid  = threadIdx.x;
  const int lane = tid & 63, wid = tid >> 6;
  const int g = lane >> 4, r = lane & 15;
  const int m0 = blockIdx.x * 128;
  const int wm = wid * 32;
  const int lrow = tid >> 3, lcol = (tid & 7) * 4;

  f32x4 acc[2][4];
#pragma unroll
  for (int i = 0; i < 2; ++i)
#pragma unroll
    for (int j = 0; j < 4; ++j) acc[i][j] = (f32x4){0.f, 0.f, 0.f, 0.f};

  for (int k0 = 0; k0 < K; k0 += 32) {
    float4 av[4], wv2[2];
#pragma unroll
    for (int p = 0; p < 4; ++p)
      av[p] = *(const float4*)&vin[(m0 + lrow + p * 32) * K + k0 + lcol];
#pragma unroll
    for (int p = 0; p < 2; ++p)
      wv2[p] = *(const float4*)&Wv[(lrow + p * 32) * K + k0 + lcol];
    __syncthreads();
#pragma unroll
    for (int p = 0; p < 4; ++p) {
      uint2v ua = {pack2bf(av[p].x, av[p].y), pack2bf(av[p].z, av[p].w)};
      *(uint2v*)&a_lds[lrow + p * 32][lcol] = ua;
    }
#pragma unroll
    for (int p = 0; p < 2; ++p) {
      uint2v uw = {pack2bf(wv2[p].x, wv2[p].y), pack2bf(wv2[p].z, wv2[p].w)};
      *(uint2v*)&b_lds[lrow + p * 32][lcol] = uw;
    }
    __syncthreads();
    bf16x8 af[2], bf[4];
#pragma unroll
    for (int t = 0; t < 2; ++t) af[t] = *(bf16x8*)&a_lds[wm + t * 16 + r][g * 8];
#pragma unroll
    for (int t = 0; t < 4; ++t) bf[t] = *(bf16x8*)&b_lds[t * 16 + r][g * 8];
#pragma unroll
    for (int mt = 0; mt < 2; ++mt)
#pragma unroll
      for (int nt = 0; nt < 4; ++nt)
        acc[mt][nt] = MFMA16(af[mt], bf[nt], acc[mt][nt]);
  }

#pragma unroll
  for (int mt = 0; mt < 2; ++mt)
#pragma unroll
    for (int nt = 0; nt < 4; ++nt) {
      const int e = nt * 16 + r;
#pragma unroll
      for (int j = 0; j < 4; ++j) {
        const int m = m0 + wm + mt * 16 + 4 * g + j;
        const int b = m >> 10, t = m & 1023;
        vsT[b * 65536 + e * 1024 + t] = __float2bfloat16(acc[mt][nt][j]);
      }
    }
}

// ---------------------------------------------------------------------------
// Kernel 3: fused attention (R8 structure), XCD-swizzled 1D grid of 8192.
//   lin = (bid&7)*1024 + (bid>>3)  [bijective: 8192 = 8*1024]
//   qb = lin&63, h = (lin>>6)&15, b = lin>>10
//   -> XCD j receives lin j*1024..j*1024+1023 = ALL of batch j's blocks,
//      h-major: its 64-block runs share one 128KB K-slice; whole-batch K
//      (2MB) + vsT (128KB) fit the XCD's 4MB L2.
// ---------------------------------------------------------------------------
__global__ __launch_bounds__(256, 4) void attn_kernel(
    const __hip_bfloat16* __restrict__ qs_, const __hip_bfloat16* __restrict__ ks_,
    const __hip_bfloat16* __restrict__ vsT_, float* __restrict__ attn_out,
    __hip_bfloat16* __restrict__ heads_)
{
  const int S = 1024, H = 16;
  const int tid = threadIdx.x, lane = tid & 63, kc = tid >> 6;
  const int g = lane >> 4, r = lane & 15;
  const int lin = ((int)blockIdx.x & 7) * 1024 + ((int)blockIdx.x >> 3);
  const int qb = lin & 63, h = (lin >> 6) & 15, b = lin >> 10;
  const int bh = b * H + h;
  const int qrow = qb * 16;

  __shared__ short p_big[4][16][260];    // per-wave P rows (stride 520B)
  __shared__ float l_lds[4][16];         // [kc][r]
  __shared__ float inv_lds[16];          // 1/l per query row
  float (*heads_ov)[16][80] = (float (*)[16][80])p_big;  // overlay after use

  const short* qsp = (const short*)qs_;
  const short* ksp = (const short*)ks_;
  const short* vsp = (const short*)vsT_;
  short* headsp = (short*)heads_;

  const int qidx = (b * S + qrow + r) * 1024 + h * 64;
  const bf16x8 qf0 = *(const bf16x8*)&qsp[qidx + g * 8];
  const bf16x8 qf1 = *(const bf16x8*)&qsp[qidx + 32 + g * 8];
  const int kbase = (b * S + kc * 256 + r) * 1024 + h * 64 + g * 8;

  // ---- QK pass over this wave's 256 keys: e packed bf16 in 32 VGPRs ----
  unsigned int pk[32];
  float lsa0 = 0.f, lsa1 = 0.f, lsa2 = 0.f, lsa3 = 0.f;
#pragma unroll
  for (int i = 0; i < 4; ++i) {      // 64 keys per iteration
    const int t0 = i * 64;
    bf16x8 kf[8];
#pragma unroll
    for (int u = 0; u < 4; ++u) {
      kf[2 * u]     = *(const bf16x8*)&ksp[kbase + (t0 + 16 * u) * 1024];
      kf[2 * u + 1] = *(const bf16x8*)&ksp[kbase + (t0 + 16 * u) * 1024 + 32];
    }
    float es[4];
#pragma unroll
    for (int u = 0; u < 4; ++u) {
      f32x4 s = (f32x4){0.f, 0.f, 0.f, 0.f};
      s = MFMA16(kf[2 * u], qf0, s);
      s = MFMA16(kf[2 * u + 1], qf1, s);
      const float e0 = __expf(s[0]), e1 = __expf(s[1]);
      const float e2 = __expf(s[2]), e3 = __expf(s[3]);
      pk[i * 8 + 2 * u]     = pack2bf(e0, e1);
      pk[i * 8 + 2 * u + 1] = pack2bf(e2, e3);
      es[u] = (e0 + e1) + (e2 + e3);
    }
    lsa0 += es[0]; lsa1 += es[1]; lsa2 += es[2]; lsa3 += es[3];
  }
  float ls = (lsa0 + lsa1) + (lsa2 + lsa3);
  ls += __shfl_xor(ls, 16);
  ls += __shfl_xor(ls, 32);          // per-lane: sum over this wave's 256 keys
  if (g == 0) l_lds[kc][r] = ls;
  __syncthreads();
  {
    const float lf = (l_lds[0][r] + l_lds[1][r]) + (l_lds[2][r] + l_lds[3][r]);
    if (kc == 0 && g == 0) inv_lds[r] = 1.f / lf;
  }

  // ---- stage ALL P to LDS; pk dies here ----
#pragma unroll
  for (int j = 0; j < 8; ++j) {
    uint2v w0 = {pk[4 * j + 0], pk[4 * j + 1]};   // keys j*32+4g..+3
    uint2v w1 = {pk[4 * j + 2], pk[4 * j + 3]};   // keys j*32+16+4g..+3
    *(uint2v*)&p_big[kc][r][j * 32 + 4 * g] = w0;
    *(uint2v*)&p_big[kc][r][j * 32 + 16 + 4 * g] = w1;
  }
  __syncthreads();                   // P + inv_lds visible

  // ---- PV loop: V loads + P b128 reads + MFMA ----
  f32x4 hacc[4];
#pragma unroll
  for (int i = 0; i < 4; ++i) hacc[i] = (f32x4){0.f, 0.f, 0.f, 0.f};
  const int vbase = b * 65536 + r * 1024 + g * 8 + kc * 256;

#pragma unroll
  for (int j = 0; j < 8; ++j) {      // 32-key tiles within the chunk
    const int tcl = j * 32;
    bf16x8 vf[4];
#pragma unroll
    for (int nt = 0; nt < 4; ++nt)
      vf[nt] = *(const bf16x8*)&vsp[vbase + nt * 16384 + tcl];
    const bf16x8 pa = *(bf16x8*)&p_big[kc][r][tcl + g * 8];
#pragma unroll
    for (int nt = 0; nt < 4; ++nt)
      hacc[nt] = MFMA16(pa, vf[nt], hacc[nt]);
  }

  // ---- attn stores: row-wise, 512B-contiguous float4 NT runs ----
  {
    const int half = lane >> 5, l32 = lane & 31;
#pragma unroll
    for (int rp = 0; rp < 8; ++rp) {
      const int row = rp * 2 + half;
      const bf16x8 pe = *(const bf16x8*)&p_big[kc][row][l32 * 8];
      const float invr = inv_lds[row];
      f32x4 o0, o1;
      o0[0] = bf2f(pe[0]) * invr; o0[1] = bf2f(pe[1]) * invr;
      o0[2] = bf2f(pe[2]) * invr; o0[3] = bf2f(pe[3]) * invr;
      o1[0] = bf2f(pe[4]) * invr; o1[1] = bf2f(pe[5]) * invr;
      o1[2] = bf2f(pe[6]) * invr; o1[3] = bf2f(pe[7]) * invr;
      const int base = ((b * S + qrow + row) * H + h) * S + kc * 256 + l32 * 8;
      __builtin_nontemporal_store(o0, (f32x4*)&attn_out[base]);
      __builtin_nontemporal_store(o1, (f32x4*)&attn_out[base + 4]);
    }
  }
  __syncthreads();                   // p_big dead -> safe to overlay

  // ---- heads partials into overlay; PV output query = ROW 4g+j ----
#pragma unroll
  for (int nt = 0; nt < 4; ++nt)
#pragma unroll
    for (int j = 0; j < 4; ++j)
      heads_ov[kc][4 * g + j][nt * 16 + r] = hacc[nt][j];
  __syncthreads();

  // ---- final: distributed 4-way sum, row-indexed normalizer, store ----
  {
    const int row = tid >> 4, c4 = (tid & 15) * 4;
    const float invr = inv_lds[row];
    short4v hv;
#pragma unroll
    for (int i = 0; i < 4; ++i) {
      const float s4 = (heads_ov[0][row][c4 + i] + heads_ov[1][row][c4 + i]) +
                       (heads_ov[2][row][c4 + i] + heads_ov[3][row][c4 + i]);
      hv[i] = f2bf(s4 * invr);
    }
    *(short4v*)&headsp[(bh * S + qrow + row) * 64 + c4] = hv;
  }
}

// ---------------------------------------------------------------------------
// Kernel 4: outputs = mean_h(heads) @ Wo^T.  grid = 512, 16 rows per block.
// ---------------------------------------------------------------------------
__global__ __launch_bounds__(256) void out_kernel(
    const __hip_bfloat16* __restrict__ heads_, const float* __restrict__ Wo,
    float* __restrict__ out)
{
  __shared__ float hm[16][64];
  const int tid = threadIdx.x;
  const int m0 = blockIdx.x * 16;
  const short* headsp = (const short*)heads_;

  {
    const int row = tid >> 4, e4 = (tid & 15) * 4;
    const int m = m0 + row, b = m >> 10, s = m & 1023;
    float a0 = 0.f, a1 = 0.f, a2 = 0.f, a3 = 0.f;
    for (int hh = 0; hh < 16; ++hh) {
      const short4v hv =
          *(const short4v*)&headsp[((b * 16 + hh) * 1024 + s) * 64 + e4];
      a0 += bf2f(hv[0]); a1 += bf2f(hv[1]); a2 += bf2f(hv[2]); a3 += bf2f(hv[3]);
    }
    const float sc = 1.f / 16.f;
    hm[row][e4 + 0] = a0 * sc; hm[row][e4 + 1] = a1 * sc;
    hm[row][e4 + 2] = a2 * sc; hm[row][e4 + 3] = a3 * sc;
  }
  __syncthreads();

  for (int c = 0; c < 4; ++c) {
    const int d = c * 256 + tid;
    float4 wo4[16];
#pragma unroll
    for (int i = 0; i < 16; ++i) wo4[i] = *(const float4*)&Wo[d * 64 + i * 4];
    for (int row = 0; row < 16; ++row) {
      float a = 0.f;
#pragma unroll
      for (int i = 0; i < 16; ++i) {
        const float4 h4 = *(const float4*)&hm[row][i * 4];
        a += h4.x * wo4[i].x + h4.y * wo4[i].y + h4.z * wo4[i].z + h4.w * wo4[i].w;
      }
      out[(m0 + row) * 1024 + d] = a;
    }
  }
}

// ---------------------------------------------------------------------------
extern "C" void kernel_launch(void* const* d_in, const int* in_sizes, int n_in,
                              void* d_out, int out_size, void* d_ws, size_t ws_size,
                              hipStream_t stream) {
  const float* q  = (const float*)d_in[0];
  const float* k  = (const float*)d_in[1];
  const float* v  = (const float*)d_in[2];
  const float* Wq = (const float*)d_in[3];
  const float* Wk = (const float*)d_in[4];
  const float* Wv = (const float*)d_in[5];
  const float* Wo = (const float*)d_in[6];

  float* out0 = (float*)d_out;                       // [8,1024,1024]
  float* attn = out0 + (size_t)8 * 1024 * 1024;      // [8,1024,16,1024]

  char* ws = (char*)d_ws;                            // 49 MB used
  __hip_bfloat16* qs    = (__hip_bfloat16*)(ws);                     // 16 MB
  __hip_bfloat16* ksbuf = (__hip_bfloat16*)(ws + (16u << 20));       // 16 MB
  __hip_bfloat16* vsT   = (__hip_bfloat16*)(ws + (32u << 20));       //  1 MB
  __hip_bfloat16* heads = (__hip_bfloat16*)(ws + (33u << 20));       // 16 MB

  dim3 blk(256);
  proj_qk_kernel<<<dim3(64, 16), blk, 0, stream>>>(q, k, Wq, Wk, qs, ksbuf);
  proj_v_kernel<<<dim3(64), blk, 0, stream>>>(v, Wv, vsT);
  attn_kernel<<<dim3(8192), blk, 0, stream>>>(qs, ksbuf, vsT, attn, heads);
  out_kernel<<<dim3(512), blk, 0, stream>>>(heads, Wo, out0);
}

// Round 13
// 421.492 us; speedup vs baseline: 3.5146x; 1.0114x over previous
//
#include <hip/hip_runtime.h>
#include <hip/hip_bf16.h>

// ---------------------------------------------------------------------------
// InterpretableMultiHeadAttention  (B=8, S=1024, D=1024, H=16, dk=64)
//   outputs [B,S,D] fp32 ; attn [B,Sq,H,Sk] fp32  (concatenated in d_out)
// Pipeline:
//   0) cvt     : q,k,Wq,Wk f32 -> bf16 (RNE), enables m97-style proj staging
//   1) proj_qk : m97 structure: BK=32, linear LDS [128][32], staging via
//                global_load_lds(16B) (2 A + 2 B instrs/wave/k-step),
//                2-barrier loop.  Fragment & C-write indexing identical to
//                the verified f32-staging kernel.  (old: ~100us/344TF,
//                bound by f32 loads + pack VALU; target ~50us)
//   2) proj_v  : vsT = (v @ Wv^T)^T  bf16 [b][e][t]   (unchanged, ~10us)
//   3) attn    : R12-verbatim (passing; 5 structural rewrites all neutral)
//   4) out     : outputs = mean_h(heads) @ Wo^T       (unchanged)
// ---------------------------------------------------------------------------

typedef __attribute__((ext_vector_type(4))) float f32x4;
typedef __attribute__((ext_vector_type(8))) short bf16x8;
typedef __attribute__((ext_vector_type(4))) short short4v;
typedef __attribute__((ext_vector_type(4))) unsigned int uint4v;
typedef __attribute__((ext_vector_type(2))) unsigned int uint2v;

#define MFMA16(a, b, c) __builtin_amdgcn_mfma_f32_16x16x32_bf16((a), (b), (c), 0, 0, 0)

// global(AS1) -> LDS(AS3) async 16B copy: lane l deposits at lds + l*16
#define GLL16(gp, lp)                                                          \
  __builtin_amdgcn_global_load_lds(                                            \
      (const __attribute__((address_space(1))) void*)(gp),                     \
      (__attribute__((address_space(3))) void*)(lp), 16, 0, 0)

__device__ __forceinline__ unsigned int rne16(float f) {
  unsigned int u = __float_as_uint(f);
  return u + 0x7fffu + ((u >> 16) & 1u);   // round-to-nearest-even in bit 16
}
__device__ __forceinline__ unsigned int pack2bf(float a, float b) {
  return (rne16(a) >> 16) | (rne16(b) & 0xffff0000u);
}
__device__ __forceinline__ short f2bf(float f) {
  return (short)(rne16(f) >> 16);
}
__device__ __forceinline__ float bf2f(short s) {
  return __uint_as_float(((unsigned int)(unsigned short)s) << 16);
}

// ---------------------------------------------------------------------------
// Kernel 0: f32 -> bf16 convert (q,k: 8M elems; Wq,Wk: 1M).  grid (4096, 4).
// ---------------------------------------------------------------------------
__global__ __launch_bounds__(256) void cvt_kernel(
    const float* __restrict__ q, const float* __restrict__ k,
    const float* __restrict__ Wq, const float* __restrict__ Wk,
    short* __restrict__ qb, short* __restrict__ kb,
    short* __restrict__ Wqb, short* __restrict__ Wkb)
{
  const int y = blockIdx.y;
  const float* src = (y == 0) ? q : (y == 1) ? k : (y == 2) ? Wq : Wk;
  short* dst = (y == 0) ? qb : (y == 1) ? kb : (y == 2) ? Wqb : Wkb;
  const int n = (y < 2) ? (8 * 1024 * 1024) : (1024 * 1024);
  const int i = (blockIdx.x * 256 + threadIdx.x) * 8;
  if (i >= n) return;
  const float4 a = *(const float4*)&src[i];
  const float4 b = *(const float4*)&src[i + 4];
  uint4v o = {pack2bf(a.x, a.y), pack2bf(a.z, a.w),
              pack2bf(b.x, b.y), pack2bf(b.z, b.w)};
  *(uint4v*)&dst[i] = o;
}

// ---------------------------------------------------------------------------
// Kernel 1: fused Q/K projection, m97-style.  A [8192,1024] bf16,
// W [1024,1024] bf16 ([out,in] = B^T), C [8192,1024] bf16.
// grid = (64, 16): y<8 -> Q (scale 1/8), else K.
// Per k-step (BK=32): each of 4 waves issues 2 A + 2 B global_load_lds
// (16 rows x 64B each), 2 barriers, then 8 ds_read_b128 + 16 MFMA.
// ---------------------------------------------------------------------------
__global__ __launch_bounds__(256) void proj_qk_kernel(
    const short* __restrict__ qb, const short* __restrict__ kb,
    const short* __restrict__ Wqb, const short* __restrict__ Wkb,
    __hip_bfloat16* __restrict__ qs, __hip_bfloat16* __restrict__ ks)
{
  const int K = 1024, N = 1024;
  __shared__ short a_lds[128 * 32];   // [row][k] linear, 64B rows
  __shared__ short b_lds[128 * 32];
  const int tid = threadIdx.x;
  const int lane = tid & 63, wid = tid >> 6;
  const int g = lane >> 4, r = lane & 15;
  const bool isK = blockIdx.y >= 8;
  const short* A = isK ? kb : qb;
  const short* W = isK ? Wkb : Wqb;
  __hip_bfloat16* C = isK ? ks : qs;
  const float scale = isK ? 1.0f : 0.125f;   // 1/sqrt(dk) folded into qs
  const int m0 = blockIdx.x * 128;
  const int n0 = (blockIdx.y & 7) * 128;
  const int wm = (wid >> 1) * 64, wn = (wid & 1) * 64;

  // staging geometry: instr covers 16 rows (4 lanes x 16B per 64B row)
  const int Ra = wid * 32;                 // this wave's 32 rows
  const int srow = lane >> 2, sslot = lane & 3;
  const long aoff0 = (long)(m0 + Ra + srow) * K + sslot * 8;
  const long aoff1 = (long)(m0 + Ra + 16 + srow) * K + sslot * 8;
  const long boff0 = (long)(n0 + Ra + srow) * K + sslot * 8;
  const long boff1 = (long)(n0 + Ra + 16 + srow) * K + sslot * 8;

  f32x4 acc[4][4];
#pragma unroll
  for (int i = 0; i < 4; ++i)
#pragma unroll
    for (int j = 0; j < 4; ++j) acc[i][j] = (f32x4){0.f, 0.f, 0.f, 0.f};

  for (int k0 = 0; k0 < K; k0 += 32) {
    __syncthreads();                       // previous step's reads done
    GLL16(A + aoff0 + k0, &a_lds[Ra * 32]);
    GLL16(A + aoff1 + k0, &a_lds[(Ra + 16) * 32]);
    GLL16(W + boff0 + k0, &b_lds[Ra * 32]);
    GLL16(W + boff1 + k0, &b_lds[(Ra + 16) * 32]);
    __syncthreads();                       // vmcnt(0) drained before barrier
    bf16x8 af[4], bf[4];
#pragma unroll
    for (int t = 0; t < 4; ++t) {
      af[t] = *(bf16x8*)&a_lds[(wm + t * 16 + r) * 32 + g * 8];
      bf[t] = *(bf16x8*)&b_lds[(wn + t * 16 + r) * 32 + g * 8];
    }
#pragma unroll
    for (int mt = 0; mt < 4; ++mt)
#pragma unroll
      for (int nt = 0; nt < 4; ++nt)
        acc[mt][nt] = MFMA16(af[mt], bf[nt], acc[mt][nt]);
  }

#pragma unroll
  for (int mt = 0; mt < 4; ++mt)
#pragma unroll
    for (int nt = 0; nt < 4; ++nt) {
      const int n = n0 + wn + nt * 16 + r;
#pragma unroll
      for (int j = 0; j < 4; ++j) {
        const int m = m0 + wm + mt * 16 + 4 * g + j;
        C[m * N + n] = __float2bfloat16(acc[mt][nt][j] * scale);
      }
    }
}

// ---------------------------------------------------------------------------
// Kernel 2: V projection, output TRANSPOSED per batch: vsT[b][e][t] bf16.
// (unchanged f32 path; only ~10us)
// ---------------------------------------------------------------------------
__global__ __launch_bounds__(256) void proj_v_kernel(
    const float* __restrict__ vin, const float* __restrict__ Wv,
    __hip_bfloat16* __restrict__ vsT)
{
  const int K = 1024;
  __shared__ short a_lds[128][40];
  __shared__ short b_lds[64][40];
  const int tid  = threadIdx.x;
  const int lane = tid & 63, wid = tid >> 6;
  const int g = lane >> 4, r = lane & 15;
  const int m0 = blockIdx.x * 128;
  const int wm = wid * 32;
  const int lrow = tid >> 3, lcol = (tid & 7) * 4;

  f32x4 acc[2][4];
#pragma unroll
  for (int i = 0; i < 2; ++i)
#pragma unroll
    for (int j = 0; j < 4; ++j) acc[i][j] = (f32x4){0.f, 0.f, 0.f, 0.f};

  for (int k0 = 0; k0 < K; k0 += 32) {
    float4 av[4], wv2[2];
#pragma unroll
    for (int p = 0; p < 4; ++p)
      av[p] = *(const float4*)&vin[(m0 + lrow + p * 32) * K + k0 + lcol];
#pragma unroll
    for (int p = 0; p < 2; ++p)
      wv2[p] = *(const float4*)&Wv[(lrow + p * 32) * K + k0 + lcol];
    __syncthreads();
#pragma unroll
    for (int p = 0; p < 4; ++p) {
      uint2v ua = {pack2bf(av[p].x, av[p].y), pack2bf(av[p].z, av[p].w)};
      *(uint2v*)&a_lds[lrow + p * 32][lcol] = ua;
    }
#pragma unroll
    for (int p = 0; p < 2; ++p) {
      uint2v uw = {pack2bf(wv2[p].x, wv2[p].y), pack2bf(wv2[p].z, wv2[p].w)};
      *(uint2v*)&b_lds[lrow + p * 32][lcol] = uw;
    }
    __syncthreads();
    bf16x8 af[2], bf[4];
#pragma unroll
    for (int t = 0; t < 2; ++t) af[t] = *(bf16x8*)&a_lds[wm + t * 16 + r][g * 8];
#pragma unroll
    for (int t = 0; t < 4; ++t) bf[t] = *(bf16x8*)&b_lds[t * 16 + r][g * 8];
#pragma unroll
    for (int mt = 0; mt < 2; ++mt)
#pragma unroll
      for (int nt = 0; nt < 4; ++nt)
        acc[mt][nt] = MFMA16(af[mt], bf[nt], acc[mt][nt]);
  }

#pragma unroll
  for (int mt = 0; mt < 2; ++mt)
#pragma unroll
    for (int nt = 0; nt < 4; ++nt) {
      const int e = nt * 16 + r;
#pragma unroll
      for (int j = 0; j < 4; ++j) {
        const int m = m0 + wm + mt * 16 + 4 * g + j;
        const int b = m >> 10, t = m & 1023;
        vsT[b * 65536 + e * 1024 + t] = __float2bfloat16(acc[mt][nt][j]);
      }
    }
}

// ---------------------------------------------------------------------------
// Kernel 3: fused attention (R12 VERBATIM).  XCD-swizzled 1D grid of 8192.
// ---------------------------------------------------------------------------
__global__ __launch_bounds__(256, 4) void attn_kernel(
    const __hip_bfloat16* __restrict__ qs_, const __hip_bfloat16* __restrict__ ks_,
    const __hip_bfloat16* __restrict__ vsT_, float* __restrict__ attn_out,
    __hip_bfloat16* __restrict__ heads_)
{
  const int S = 1024, H = 16;
  const int tid = threadIdx.x, lane = tid & 63, kc = tid >> 6;
  const int g = lane >> 4, r = lane & 15;
  const int lin = ((int)blockIdx.x & 7) * 1024 + ((int)blockIdx.x >> 3);
  const int qb = lin & 63, h = (lin >> 6) & 15, b = lin >> 10;
  const int bh = b * H + h;
  const int qrow = qb * 16;

  __shared__ short p_big[4][16][260];    // per-wave P rows (stride 520B)
  __shared__ float l_lds[4][16];         // [kc][r]
  __shared__ float inv_lds[16];          // 1/l per query row
  float (*heads_ov)[16][80] = (float (*)[16][80])p_big;  // overlay after use

  const short* qsp = (const short*)qs_;
  const short* ksp = (const short*)ks_;
  const short* vsp = (const short*)vsT_;
  short* headsp = (short*)heads_;

  const int qidx = (b * S + qrow + r) * 1024 + h * 64;
  const bf16x8 qf0 = *(const bf16x8*)&qsp[qidx + g * 8];
  const bf16x8 qf1 = *(const bf16x8*)&qsp[qidx + 32 + g * 8];
  const int kbase = (b * S + kc * 256 + r) * 1024 + h * 64 + g * 8;

  // ---- QK pass over this wave's 256 keys: e packed bf16 in 32 VGPRs ----
  unsigned int pk[32];
  float lsa0 = 0.f, lsa1 = 0.f, lsa2 = 0.f, lsa3 = 0.f;
#pragma unroll
  for (int i = 0; i < 4; ++i) {      // 64 keys per iteration
    const int t0 = i * 64;
    bf16x8 kf[8];
#pragma unroll
    for (int u = 0; u < 4; ++u) {
      kf[2 * u]     = *(const bf16x8*)&ksp[kbase + (t0 + 16 * u) * 1024];
      kf[2 * u + 1] = *(const bf16x8*)&ksp[kbase + (t0 + 16 * u) * 1024 + 32];
    }
    float es[4];
#pragma unroll
    for (int u = 0; u < 4; ++u) {
      f32x4 s = (f32x4){0.f, 0.f, 0.f, 0.f};
      s = MFMA16(kf[2 * u], qf0, s);
      s = MFMA16(kf[2 * u + 1], qf1, s);
      const float e0 = __expf(s[0]), e1 = __expf(s[1]);
      const float e2 = __expf(s[2]), e3 = __expf(s[3]);
      pk[i * 8 + 2 * u]     = pack2bf(e0, e1);
      pk[i * 8 + 2 * u + 1] = pack2bf(e2, e3);
      es[u] = (e0 + e1) + (e2 + e3);
    }
    lsa0 += es[0]; lsa1 += es[1]; lsa2 += es[2]; lsa3 += es[3];
  }
  float ls = (lsa0 + lsa1) + (lsa2 + lsa3);
  ls += __shfl_xor(ls, 16);
  ls += __shfl_xor(ls, 32);          // per-lane: sum over this wave's 256 keys
  if (g == 0) l_lds[kc][r] = ls;
  __syncthreads();
  {
    const float lf = (l_lds[0][r] + l_lds[1][r]) + (l_lds[2][r] + l_lds[3][r]);
    if (kc == 0 && g == 0) inv_lds[r] = 1.f / lf;
  }

  // ---- stage ALL P to LDS; pk dies here ----
#pragma unroll
  for (int j = 0; j < 8; ++j) {
    uint2v w0 = {pk[4 * j + 0], pk[4 * j + 1]};   // keys j*32+4g..+3
    uint2v w1 = {pk[4 * j + 2], pk[4 * j + 3]};   // keys j*32+16+4g..+3
    *(uint2v*)&p_big[kc][r][j * 32 + 4 * g] = w0;
    *(uint2v*)&p_big[kc][r][j * 32 + 16 + 4 * g] = w1;
  }
  __syncthreads();                   // P + inv_lds visible

  // ---- PV loop: V loads + P b128 reads + MFMA ----
  f32x4 hacc[4];
#pragma unroll
  for (int i = 0; i < 4; ++i) hacc[i] = (f32x4){0.f, 0.f, 0.f, 0.f};
  const int vbase = b * 65536 + r * 1024 + g * 8 + kc * 256;

#pragma unroll
  for (int j = 0; j < 8; ++j) {      // 32-key tiles within the chunk
    const int tcl = j * 32;
    bf16x8 vf[4];
#pragma unroll
    for (int nt = 0; nt < 4; ++nt)
      vf[nt] = *(const bf16x8*)&vsp[vbase + nt * 16384 + tcl];
    const bf16x8 pa = *(bf16x8*)&p_big[kc][r][tcl + g * 8];
#pragma unroll
    for (int nt = 0; nt < 4; ++nt)
      hacc[nt] = MFMA16(pa, vf[nt], hacc[nt]);
  }

  // ---- attn stores: row-wise, 512B-contiguous float4 NT runs ----
  {
    const int half = lane >> 5, l32 = lane & 31;
#pragma unroll
    for (int rp = 0; rp < 8; ++rp) {
      const int row = rp * 2 + half;
      const bf16x8 pe = *(const bf16x8*)&p_big[kc][row][l32 * 8];
      const float invr = inv_lds[row];
      f32x4 o0, o1;
      o0[0] = bf2f(pe[0]) * invr; o0[1] = bf2f(pe[1]) * invr;
      o0[2] = bf2f(pe[2]) * invr; o0[3] = bf2f(pe[3]) * invr;
      o1[0] = bf2f(pe[4]) * invr; o1[1] = bf2f(pe[5]) * invr;
      o1[2] = bf2f(pe[6]) * invr; o1[3] = bf2f(pe[7]) * invr;
      const int base = ((b * S + qrow + row) * H + h) * S + kc * 256 + l32 * 8;
      __builtin_nontemporal_store(o0, (f32x4*)&attn_out[base]);
      __builtin_nontemporal_store(o1, (f32x4*)&attn_out[base + 4]);
    }
  }
  __syncthreads();                   // p_big dead -> safe to overlay

  // ---- heads partials into overlay; PV output query = ROW 4g+j ----
#pragma unroll
  for (int nt = 0; nt < 4; ++nt)
#pragma unroll
    for (int j = 0; j < 4; ++j)
      heads_ov[kc][4 * g + j][nt * 16 + r] = hacc[nt][j];
  __syncthreads();

  // ---- final: distributed 4-way sum, row-indexed normalizer, store ----
  {
    const int row = tid >> 4, c4 = (tid & 15) * 4;
    const float invr = inv_lds[row];
    short4v hv;
#pragma unroll
    for (int i = 0; i < 4; ++i) {
      const float s4 = (heads_ov[0][row][c4 + i] + heads_ov[1][row][c4 + i]) +
                       (heads_ov[2][row][c4 + i] + heads_ov[3][row][c4 + i]);
      hv[i] = f2bf(s4 * invr);
    }
    *(short4v*)&headsp[(bh * S + qrow + row) * 64 + c4] = hv;
  }
}

// ---------------------------------------------------------------------------
// Kernel 4: outputs = mean_h(heads) @ Wo^T.  grid = 512, 16 rows per block.
// ---------------------------------------------------------------------------
__global__ __launch_bounds__(256) void out_kernel(
    const __hip_bfloat16* __restrict__ heads_, const float* __restrict__ Wo,
    float* __restrict__ out)
{
  __shared__ float hm[16][64];
  const int tid = threadIdx.x;
  const int m0 = blockIdx.x * 16;
  const short* headsp = (const short*)heads_;

  {
    const int row = tid >> 4, e4 = (tid & 15) * 4;
    const int m = m0 + row, b = m >> 10, s = m & 1023;
    float a0 = 0.f, a1 = 0.f, a2 = 0.f, a3 = 0.f;
    for (int hh = 0; hh < 16; ++hh) {
      const short4v hv =
          *(const short4v*)&headsp[((b * 16 + hh) * 1024 + s) * 64 + e4];
      a0 += bf2f(hv[0]); a1 += bf2f(hv[1]); a2 += bf2f(hv[2]); a3 += bf2f(hv[3]);
    }
    const float sc = 1.f / 16.f;
    hm[row][e4 + 0] = a0 * sc; hm[row][e4 + 1] = a1 * sc;
    hm[row][e4 + 2] = a2 * sc; hm[row][e4 + 3] = a3 * sc;
  }
  __syncthreads();

  for (int c = 0; c < 4; ++c) {
    const int d = c * 256 + tid;
    float4 wo4[16];
#pragma unroll
    for (int i = 0; i < 16; ++i) wo4[i] = *(const float4*)&Wo[d * 64 + i * 4];
    for (int row = 0; row < 16; ++row) {
      float a = 0.f;
#pragma unroll
      for (int i = 0; i < 16; ++i) {
        const float4 h4 = *(const float4*)&hm[row][i * 4];
        a += h4.x * wo4[i].x + h4.y * wo4[i].y + h4.z * wo4[i].z + h4.w * wo4[i].w;
      }
      out[(m0 + row) * 1024 + d] = a;
    }
  }
}

// ---------------------------------------------------------------------------
extern "C" void kernel_launch(void* const* d_in, const int* in_sizes, int n_in,
                              void* d_out, int out_size, void* d_ws, size_t ws_size,
                              hipStream_t stream) {
  const float* q  = (const float*)d_in[0];
  const float* k  = (const float*)d_in[1];
  const float* v  = (const float*)d_in[2];
  const float* Wq = (const float*)d_in[3];
  const float* Wk = (const float*)d_in[4];
  const float* Wv = (const float*)d_in[5];
  const float* Wo = (const float*)d_in[6];

  float* out0 = (float*)d_out;                       // [8,1024,1024]
  float* attn = out0 + (size_t)8 * 1024 * 1024;      // [8,1024,16,1024]

  char* ws = (char*)d_ws;
  __hip_bfloat16* qs    = (__hip_bfloat16*)(ws);                     // 16 MB
  __hip_bfloat16* ksbuf = (__hip_bfloat16*)(ws + (16u << 20));       // 16 MB
  __hip_bfloat16* vsT   = (__hip_bfloat16*)(ws + (32u << 20));       //  1 MB
  __hip_bfloat16* heads = (__hip_bfloat16*)(ws + (33u << 20));       // 16 MB
  // converted bf16 inputs: qb ALIASES heads (dead until attn runs, and
  // qb is fully consumed by proj_qk before attn starts -- stream ordered)
  short* qbuf  = (short*)(ws + (33u << 20));                         // 16 MB
  short* kbuf  = (short*)(ws + (49u << 20));                         // 16 MB
  short* Wqbuf = (short*)(ws + (65u << 20));                         //  2 MB
  short* Wkbuf = (short*)(ws + (67u << 20));                         //  2 MB

  dim3 blk(256);
  cvt_kernel<<<dim3(4096, 4), blk, 0, stream>>>(q, k, Wq, Wk,
                                                qbuf, kbuf, Wqbuf, Wkbuf);
  proj_qk_kernel<<<dim3(64, 16), blk, 0, stream>>>(qbuf, kbuf, Wqbuf, Wkbuf,
                                                   qs, ksbuf);
  proj_v_kernel<<<dim3(64), blk, 0, stream>>>(v, Wv, vsT);
  attn_kernel<<<dim3(8192), blk, 0, stream>>>(qs, ksbuf, vsT, attn, heads);
  out_kernel<<<dim3(512), blk, 0, stream>>>(heads, Wo, out0);
}